// Round 23
// baseline (171.995 us; speedup 1.0000x reference)
//
#include <hip/hip_runtime.h>
#include <math.h>

#define BLKSZ 160
#define NWT   64
#define WTLEN 512
#define FPB   8       // frames per main block
#define SPB   1280    // samples per main block (8*160) = 5 bs1-rows exactly
#define NTHR  256     // 4 waves
#define SMP   12      // smT row pitch (floats)
#define NREP  4       // measurement probe: repeat k_main body 4x (identical work)

// ReduceWindowRewriter(base_length=16) level sizes for T=960000
#define NB1   3750    // T/256
#define NB2   235
#define NB2P  240
#define NB3   15      // < 16 -> naive sequential top scan

// +1-per-16 padded LDS index: stride-16 rows -> stride-17 (all 32 banks)
#define PRI(a)  ((a) + ((a) >> 4))

// f32 increment exactly as the reference: (pitch / 16000) * 512
static __device__ __forceinline__ float inc32_of(float p) {
    return (p / 16000.0f) * 512.0f;
}

// K1: blocks [0,235): leaf tree -> bs1 (16) + bs2 (1). blocks [235,363): wts_eff.
__global__ __launch_bounds__(256) void k_leaf(
    const float* __restrict__ pitch, const float* __restrict__ wts,
    float* __restrict__ bs1, float* __restrict__ bs2,
    float* __restrict__ wts_eff, int T)
{
    int t = threadIdx.x;
    if (blockIdx.x >= NB2) {                      // wts_eff part
        int i = (blockIdx.x - NB2) * 256 + t;
        if (i < NWT * WTLEN) {
            float v = wts[i];
            if ((i >> 9) >= 4) v = tanhf(v);
            wts_eff[i] = v;
        }
        return;
    }
    __shared__ float b0[256];
    __shared__ float b1[16];
    int blk = blockIdx.x;
    size_t s0 = (size_t)blk * 4096;
    int nsamp = min(4096, T - (int)s0);
    int nb0 = nsamp >> 4;                         // 256 or 96
    if (t < nb0) {                                // bs0: seq 16-chain of incs
        const float4* p4 = (const float4*)(pitch + s0 + (size_t)t * 16);
        float acc = 0.f;
        #pragma unroll
        for (int i = 0; i < 4; ++i) {
            float4 v = p4[i];
            acc = acc + inc32_of(v.x);
            acc = acc + inc32_of(v.y);
            acc = acc + inc32_of(v.z);
            acc = acc + inc32_of(v.w);
        }
        b0[t] = acc;
    }
    __syncthreads();
    int nb1 = nb0 >> 4;                           // 16 or 6
    if (t < nb1) {                                // bs1: seq 16-chain of bs0
        float acc = b0[t * 16];
        for (int j = 1; j < 16; ++j) acc = acc + b0[t * 16 + j];
        b1[t] = acc;
        bs1[blk * 16 + t] = acc;
    }
    __syncthreads();
    if (t == 0) {                                 // bs2: seq chain (pad -> skip, exact)
        float acc = b1[0];
        for (int j = 1; j < nb1; ++j) acc = acc + b1[j];
        bs2[blk] = acc;
    }
}

// K2: R20's 3-barrier k_main, body repeated NREP times (measurement probe).
__global__ __launch_bounds__(256) void k_main(
    const float* __restrict__ pitch, const float* __restrict__ amp,
    const float* __restrict__ att, const float* __restrict__ wts_eff,
    const float* __restrict__ bs1g, const float* __restrict__ bs2g,
    float* __restrict__ out, int frames)
{
    __shared__ float smT[NWT][SMP];         // 3 KB
    __shared__ float mixrow[FPB][WTLEN];    // 16 KB
    __shared__ float pr[SPB + SPB / 16];    // 5.3 KB, padded indexing
    __shared__ float roffL[SPB / 16];       // 80
    __shared__ float bs2L[NB2P];            // zero-padded
    __shared__ float bs1w[32];              // bs1 rows rlo, rlo+1
    __shared__ float bs3L[NB3];
    __shared__ float S4L[NB3];
    __shared__ float S3w[2];
    __shared__ float S2w[6];
    __shared__ float bs1prevL;

    int tid = threadIdx.x, lane = tid & 63, wv = tid >> 6;   // wv in [0,4)
    int b = blockIdx.x;
    int f0 = b * FPB;
    size_t base = (size_t)b * SPB;
    int j0 = 5 * b - 2;                     // S2 window start
    int rlo = max(j0, 0) >> 4;              // bs1-row window base for S2

    for (int rep = 0; rep < NREP; ++rep) {
        // ======== phase 1: softmax + staging + window loads ========
        #pragma unroll
        for (int r = 0; r < 2; ++r) {
            int f = f0 + wv * 2 + r;
            float a = att[(size_t)lane * frames + f];
            float m = a;
            #pragma unroll
            for (int off = 32; off; off >>= 1) m = fmaxf(m, __shfl_xor(m, off, 64));
            float e = expf(a - m);
            float s = e;
            #pragma unroll
            for (int off = 32; off; off >>= 1) s += __shfl_xor(s, off, 64);
            smT[lane][wv * 2 + r] = e / s;
        }

        float increg[SPB / NTHR];
        #pragma unroll
        for (int i = 0; i < SPB / NTHR; ++i) {
            increg[i] = inc32_of(pitch[base + i * NTHR + tid]);
            pr[PRI(i * NTHR + tid)] = increg[i];
        }
        if (tid < NB2P) {
            bs2L[tid] = (tid < NB2) ? bs2g[tid] : 0.f;
        } else {                            // 16 spare threads: 2 bs1w loads each
            int i = tid - NB2P;             // 0..15
            #pragma unroll
            for (int k = 0; k < 2; ++k) {
                int idx = i * 2 + k;        // 0..31
                int g = rlo * 16 + idx;
                bs1w[idx] = (g < NB1) ? bs1g[g] : 0.f;
            }
        }
        if (tid == 224) bs1prevL = (b > 0) ? bs1g[5 * b - 1] : 0.f;
        __syncthreads();                    // barrier A

        // ======== phase 2: scan lanes + in-wave ladder, then all lanes mixrow ====
        if (tid < SPB / 16) {
            int a0 = tid * 17;              // PRI(tid*16 + j) = tid*17 + j
            float acc = pr[a0];
            for (int j = 1; j < 16; ++j) { acc = acc + pr[a0 + j]; pr[a0 + j] = acc; }
        } else if (tid >= 80 && tid < 80 + NB3) {
            int r = tid - 80;               // bs3 on wave-1 lanes 16..30
            float a = bs2L[r * 16];
            for (int j = 1; j < 16; ++j) a = a + bs2L[r * 16 + j];
            bs3L[r] = a;
        }
        if (tid == 80) {                    // S4 (in-wave after bs3)
            float a = 0.f;
            for (int i = 0; i < NB3; ++i) { a = a + bs3L[i]; S4L[i] = a; }
        }
        if (tid >= 80 && tid < 82) {        // the two S3 values
            int r = rlo - 1 + (tid - 80);
            float v = 0.f;
            if (r >= 0 && r < NB2) {
                int g = r >> 4, p = r & 15;
                float a = bs2L[g * 16];
                for (int k = 1; k <= p; ++k) a = a + bs2L[g * 16 + k];
                v = g ? (a + S4L[g - 1]) : a;
            }
            S3w[tid - 80] = v;
        }
        if (tid >= 80 && tid < 86) {        // the 6 S2 values
            int j = j0 + (tid - 80);
            float v = 0.f;
            if (j >= 0) {
                int r = j >> 4, p = j & 15;
                int o = (r - rlo) * 16;
                float a = bs1w[o];
                for (int q = 1; q <= p; ++q) a = a + bs1w[o + q];
                v = r ? (a + S3w[r - rlo]) : a;
            }
            S2w[tid - 80] = v;
        }
        {
            #pragma unroll
            for (int it = 0; it < 2; ++it) {
                int j = tid + it * NTHR;
                float acc[FPB];
                #pragma unroll
                for (int k = 0; k < FPB; ++k) acc[k] = 0.f;
                for (int w = 0; w < NWT; ++w) {
                    float v = wts_eff[w * WTLEN + j];
                    float4 s0 = *(const float4*)&smT[w][0];
                    float4 s1 = *(const float4*)&smT[w][4];
                    acc[0] += s0.x * v;  acc[1] += s0.y * v;
                    acc[2] += s0.z * v;  acc[3] += s0.w * v;
                    acc[4] += s1.x * v;  acc[5] += s1.y * v;
                    acc[6] += s1.z * v;  acc[7] += s1.w * v;
                }
                #pragma unroll
                for (int k = 0; k < FPB; ++k) mixrow[k][j] = acc[k];
            }
        }
        __syncthreads();                    // barrier B

        // ======== phase 3: roffL (80 threads) ========
        if (tid < SPB / 16) {
            float v;
            if (tid == 0) {
                v = (b == 0) ? 0.f : (bs1prevL + S2w[0]);
            } else {
                int lr = (tid - 1) >> 4;
                int p  = (tid - 1) & 15;
                float acc = pr[(lr * 16) * 17 + 15];  // PRI(row*16+15) = row*17+15
                for (int q = 1; q <= p; ++q) acc = acc + pr[(lr * 16 + q) * 17 + 15];
                int gr = 5 * b + lr;
                v = gr ? (acc + S2w[lr + 1]) : acc;
            }
            roffL[tid] = v;
        }
        __syncthreads();                    // barrier C

        // ======== phase 4: per-sample finish ========
        #pragma unroll
        for (int i = 0; i < SPB / NTHR; ++i) {
            int tl = i * NTHR + tid;
            size_t tg = base + tl;
            float C = pr[PRI(tl)] + roffL[tl >> 4];
            float sub = C - increg[i];
            float idx = fmodf(sub, 512.0f);
            if (idx < 0.f) idx += 512.f;
            int li = (int)idx;
            float alpha = idx - (float)li;
            int hi = ((int)ceilf(idx)) & (WTLEN - 1);
            int fr = tl / BLKSZ;
            float wlo = mixrow[fr][li];
            float whi = mixrow[fr][hi];
            out[tg] = (wlo + alpha * (whi - wlo)) * amp[tg];
        }
        __syncthreads();                    // LDS safe for next rep
    }
}

extern "C" void kernel_launch(void* const* d_in, const int* in_sizes, int n_in,
                              void* d_out, int out_size, void* d_ws, size_t ws_size,
                              hipStream_t stream) {
    const float* pitch = (const float*)d_in[0];
    const float* amp   = (const float*)d_in[1];
    const float* wts   = (const float*)d_in[2];
    const float* att   = (const float*)d_in[3];

    int T      = in_sizes[0];        // 960000
    int frames = T / BLKSZ;          // 6000
    int nmain  = T / SPB;            // 750

    float* ws      = (float*)d_ws;
    float* wts_eff = ws;                     // 32768 floats
    float* bs1     = ws + 32768;             // 3750 (pad 3840)
    float* bs2     = ws + 32768 + 3840;      // 235  (pad 256)
    float* out     = (float*)d_out;

    int nwts_blocks = (NWT * WTLEN + 255) / 256;       // 128
    k_leaf<<<NB2 + nwts_blocks, 256, 0, stream>>>(pitch, wts, bs1, bs2, wts_eff, T);
    k_main<<<nmain, 256, 0, stream>>>(pitch, amp, att, wts_eff, bs1, bs2, out, frames);
}

// Round 24
// 36.951 us; speedup vs baseline: 4.6547x; 4.6547x over previous
//
#include <hip/hip_runtime.h>
#include <math.h>

#define BLKSZ 160
#define NWT   64
#define WTLEN 512
#define FPB   8       // frames per main block
#define SPB   1280    // samples per main block (8*160) = 5 bs1-rows exactly
#define NTHR  256     // 4 waves
#define MFPB  16      // frames per mix block
#define SMP   20      // smT row pitch (floats), 16B-aligned

// ReduceWindowRewriter(base_length=16) level sizes for T=960000
#define NB1   3750    // T/256
#define NB2   235
#define NB2P  240
#define NB3   15      // < 16 -> naive sequential top scan

// +1-per-16 padded LDS index: stride-16 rows -> stride-17 (all 32 banks)
#define PRI(a)  ((a) + ((a) >> 4))

// f32 increment exactly as the reference: (pitch / 16000) * 512
static __device__ __forceinline__ float inc32_of(float p) {
    return (p / 16000.0f) * 512.0f;
}

// K1: blocks [0,235): leaf tree -> bs1 (16) + bs2 (1). blocks [235,363): wts_eff.
__global__ __launch_bounds__(256) void k_leaf(
    const float* __restrict__ pitch, const float* __restrict__ wts,
    float* __restrict__ bs1, float* __restrict__ bs2,
    float* __restrict__ wts_eff, int T)
{
    int t = threadIdx.x;
    if (blockIdx.x >= NB2) {                      // wts_eff part
        int i = (blockIdx.x - NB2) * 256 + t;
        if (i < NWT * WTLEN) {
            float v = wts[i];
            if ((i >> 9) >= 4) v = tanhf(v);
            wts_eff[i] = v;
        }
        return;
    }
    __shared__ float b0[256];
    __shared__ float b1[16];
    int blk = blockIdx.x;
    size_t s0 = (size_t)blk * 4096;
    int nsamp = min(4096, T - (int)s0);
    int nb0 = nsamp >> 4;                         // 256 or 96
    if (t < nb0) {                                // bs0: seq 16-chain of incs
        const float4* p4 = (const float4*)(pitch + s0 + (size_t)t * 16);
        float acc = 0.f;
        #pragma unroll
        for (int i = 0; i < 4; ++i) {
            float4 v = p4[i];
            acc = acc + inc32_of(v.x);
            acc = acc + inc32_of(v.y);
            acc = acc + inc32_of(v.z);
            acc = acc + inc32_of(v.w);
        }
        b0[t] = acc;
    }
    __syncthreads();
    int nb1 = nb0 >> 4;                           // 16 or 6
    if (t < nb1) {                                // bs1: seq 16-chain of bs0
        float acc = b0[t * 16];
        for (int j = 1; j < 16; ++j) acc = acc + b0[t * 16 + j];
        b1[t] = acc;
        bs1[blk * 16 + t] = acc;
    }
    __syncthreads();
    if (t == 0) {                                 // bs2: seq chain (pad -> skip, exact)
        float acc = b1[0];
        for (int j = 1; j < nb1; ++j) acc = acc + b1[j];
        bs2[blk] = acc;
    }
}

// K2: softmax (per frame, identical ops) + mix GEMM -> mixg[frames][512].
//     One block per 16 frames; pure-throughput, barrier-light.
__global__ __launch_bounds__(256) void k_mix(
    const float* __restrict__ att, const float* __restrict__ wts_eff,
    float* __restrict__ mixg, int frames)
{
    __shared__ float smT[NWT][SMP];
    int tid = threadIdx.x, lane = tid & 63, wv = tid >> 6;   // wv in [0,4)
    int f0 = blockIdx.x * MFPB;

    // softmax: 4 waves x 4 frames; lane = wavetable (same per-frame fl ops)
    #pragma unroll
    for (int r = 0; r < 4; ++r) {
        int f = f0 + wv * 4 + r;
        float a = att[(size_t)lane * frames + f];
        float m = a;
        #pragma unroll
        for (int off = 32; off; off >>= 1) m = fmaxf(m, __shfl_xor(m, off, 64));
        float e = expf(a - m);
        float s = e;
        #pragma unroll
        for (int off = 32; off; off >>= 1) s += __shfl_xor(s, off, 64);
        smT[lane][wv * 4 + r] = e / s;
    }
    __syncthreads();

    // mix: thread does j = tid, tid+256; w ascending; same per-(w,k) fl chain
    #pragma unroll
    for (int it = 0; it < 2; ++it) {
        int j = tid + it * NTHR;
        float acc[MFPB];
        #pragma unroll
        for (int k = 0; k < MFPB; ++k) acc[k] = 0.f;
        for (int w = 0; w < NWT; ++w) {
            float v = wts_eff[w * WTLEN + j];
            float4 s0 = *(const float4*)&smT[w][0];
            float4 s1 = *(const float4*)&smT[w][4];
            float4 s2 = *(const float4*)&smT[w][8];
            float4 s3 = *(const float4*)&smT[w][12];
            acc[0]  += s0.x * v;  acc[1]  += s0.y * v;
            acc[2]  += s0.z * v;  acc[3]  += s0.w * v;
            acc[4]  += s1.x * v;  acc[5]  += s1.y * v;
            acc[6]  += s1.z * v;  acc[7]  += s1.w * v;
            acc[8]  += s2.x * v;  acc[9]  += s2.y * v;
            acc[10] += s2.z * v;  acc[11] += s2.w * v;
            acc[12] += s3.x * v;  acc[13] += s3.y * v;
            acc[14] += s3.z * v;  acc[15] += s3.w * v;
        }
        #pragma unroll
        for (int k = 0; k < MFPB; ++k)
            mixg[(size_t)(f0 + k) * WTLEN + j] = acc[k];
    }
}

// K3: stage incs + mixg rows -> ladder -> prefixes -> lerp -> amp (no GEMM)
__global__ __launch_bounds__(256) void k_main(
    const float* __restrict__ pitch, const float* __restrict__ amp,
    const float* __restrict__ mixg, const float* __restrict__ bs1g,
    const float* __restrict__ bs2g, float* __restrict__ out, int frames)
{
    __shared__ float mixrow[FPB * WTLEN];   // 16 KB (flat; row fr at fr*512)
    __shared__ float pr[SPB + SPB / 16];    // 5.3 KB, padded indexing
    __shared__ float roffL[SPB / 16];       // 80
    __shared__ float bs2L[NB2P];            // zero-padded
    __shared__ float bs1w[32];              // bs1 rows rlo, rlo+1
    __shared__ float bs3L[NB3];
    __shared__ float S4L[NB3];
    __shared__ float S3w[2];
    __shared__ float S2w[6];
    __shared__ float bs1prevL;

    int tid = threadIdx.x;
    int b = blockIdx.x;
    size_t base = (size_t)b * SPB;
    int j0 = 5 * b - 2;                     // S2 window start
    int rlo = max(j0, 0) >> 4;              // bs1-row window base for S2

    // ======== phase 1: stage incs + mixg rows + window loads ========
    float increg[SPB / NTHR];
    #pragma unroll
    for (int i = 0; i < SPB / NTHR; ++i) {
        increg[i] = inc32_of(pitch[base + i * NTHR + tid]);
        pr[PRI(i * NTHR + tid)] = increg[i];
    }
    {
        const float4* src = (const float4*)(mixg + (size_t)b * (FPB * WTLEN));
        float4* dst = (float4*)mixrow;
        #pragma unroll
        for (int it = 0; it < 4; ++it)
            dst[it * NTHR + tid] = src[it * NTHR + tid];
    }
    if (tid < NB2P) {
        bs2L[tid] = (tid < NB2) ? bs2g[tid] : 0.f;
    } else {                                // 16 spare threads: 2 bs1w loads each
        int i = tid - NB2P;                 // 0..15
        #pragma unroll
        for (int k = 0; k < 2; ++k) {
            int idx = i * 2 + k;            // 0..31
            int g = rlo * 16 + idx;
            bs1w[idx] = (g < NB1) ? bs1g[g] : 0.f;
        }
    }
    if (tid == 224) bs1prevL = (b > 0) ? bs1g[5 * b - 1] : 0.f;
    __syncthreads();                        // barrier A

    // ======== phase 2: prefixes (80 thr) + in-wave ladder (wave 1) ========
    if (tid < SPB / 16) {
        int a0 = tid * 17;                  // PRI(tid*16 + j) = tid*17 + j
        float acc = pr[a0];
        for (int j = 1; j < 16; ++j) { acc = acc + pr[a0 + j]; pr[a0 + j] = acc; }
    } else if (tid >= 80 && tid < 80 + NB3) {
        int r = tid - 80;                   // bs3 on wave-1 lanes 16..30
        float a = bs2L[r * 16];
        for (int j = 1; j < 16; ++j) a = a + bs2L[r * 16 + j];
        bs3L[r] = a;
    }
    if (tid == 80) {                        // S4 (in-wave after bs3)
        float a = 0.f;
        for (int i = 0; i < NB3; ++i) { a = a + bs3L[i]; S4L[i] = a; }
    }
    if (tid >= 80 && tid < 82) {            // the two S3 values
        int r = rlo - 1 + (tid - 80);
        float v = 0.f;
        if (r >= 0 && r < NB2) {
            int g = r >> 4, p = r & 15;
            float a = bs2L[g * 16];
            for (int k = 1; k <= p; ++k) a = a + bs2L[g * 16 + k];
            v = g ? (a + S4L[g - 1]) : a;
        }
        S3w[tid - 80] = v;
    }
    if (tid >= 80 && tid < 86) {            // the 6 S2 values
        int j = j0 + (tid - 80);
        float v = 0.f;
        if (j >= 0) {
            int r = j >> 4, p = j & 15;
            int o = (r - rlo) * 16;
            float a = bs1w[o];
            for (int q = 1; q <= p; ++q) a = a + bs1w[o + q];
            v = r ? (a + S3w[r - rlo]) : a;
        }
        S2w[tid - 80] = v;
    }
    __syncthreads();                        // barrier B

    // ======== phase 3: roffL (80 threads) ========
    if (tid < SPB / 16) {
        float v;
        if (tid == 0) {
            v = (b == 0) ? 0.f : (bs1prevL + S2w[0]);
        } else {
            int lr = (tid - 1) >> 4;
            int p  = (tid - 1) & 15;
            float acc = pr[(lr * 16) * 17 + 15];      // PRI(row*16+15) = row*17+15
            for (int q = 1; q <= p; ++q) acc = acc + pr[(lr * 16 + q) * 17 + 15];
            int gr = 5 * b + lr;
            v = gr ? (acc + S2w[lr + 1]) : acc;
        }
        roffL[tid] = v;
    }
    __syncthreads();                        // barrier C

    // ======== phase 4: per-sample finish ========
    #pragma unroll
    for (int i = 0; i < SPB / NTHR; ++i) {
        int tl = i * NTHR + tid;
        size_t tg = base + tl;
        float C = pr[PRI(tl)] + roffL[tl >> 4];
        float sub = C - increg[i];
        float idx = fmodf(sub, 512.0f);
        if (idx < 0.f) idx += 512.f;
        int li = (int)idx;
        float alpha = idx - (float)li;
        int hi = ((int)ceilf(idx)) & (WTLEN - 1);
        int fr = tl / BLKSZ;
        float wlo = mixrow[fr * WTLEN + li];
        float whi = mixrow[fr * WTLEN + hi];
        out[tg] = (wlo + alpha * (whi - wlo)) * amp[tg];
    }
}

extern "C" void kernel_launch(void* const* d_in, const int* in_sizes, int n_in,
                              void* d_out, int out_size, void* d_ws, size_t ws_size,
                              hipStream_t stream) {
    const float* pitch = (const float*)d_in[0];
    const float* amp   = (const float*)d_in[1];
    const float* wts   = (const float*)d_in[2];
    const float* att   = (const float*)d_in[3];

    int T      = in_sizes[0];        // 960000
    int frames = T / BLKSZ;          // 6000
    int nmain  = T / SPB;            // 750
    int nmix   = frames / MFPB;      // 375

    float* ws      = (float*)d_ws;
    float* wts_eff = ws;                     // 32768 floats
    float* bs1     = ws + 32768;             // 3750 (pad 3840)
    float* bs2     = ws + 32768 + 3840;      // 235  (pad 256)
    float* mixg    = ws + 32768 + 3840 + 256;// frames*512 floats (12.3 MB)
    float* out     = (float*)d_out;

    int nwts_blocks = (NWT * WTLEN + 255) / 256;       // 128
    k_leaf<<<NB2 + nwts_blocks, 256, 0, stream>>>(pitch, wts, bs1, bs2, wts_eff, T);
    k_mix <<<nmix, 256, 0, stream>>>(att, wts_eff, mixg, frames);
    k_main<<<nmain, 256, 0, stream>>>(pitch, amp, mixg, bs1, bs2, out, frames);
}

// Round 25
// 23.344 us; speedup vs baseline: 7.3679x; 1.5829x over previous
//
#include <hip/hip_runtime.h>
#include <math.h>

#define BLKSZ 160
#define NWT   64
#define WTLEN 512
#define FPB   8       // frames per main block
#define SPB   1280    // samples per main block (8*160) = 5 bs1-rows exactly
#define NTHR  256     // 4 waves
#define SMP   12      // smT row pitch (floats)

// ReduceWindowRewriter(base_length=16) level sizes for T=960000
#define NB1   3750    // T/256
#define NB2   235
#define NB2P  240
#define NB3   15      // < 16 -> naive sequential top scan

// +1-per-16 padded LDS index: stride-16 rows -> stride-17 (all 32 banks)
#define PRI(a)  ((a) + ((a) >> 4))

// f32 increment exactly as the reference: (pitch / 16000) * 512
static __device__ __forceinline__ float inc32_of(float p) {
    return (p / 16000.0f) * 512.0f;
}

// K1: blocks [0,235): leaf tree -> bs1 (16) + bs2 (1). blocks [235,363): wts_eff.
__global__ __launch_bounds__(256) void k_leaf(
    const float* __restrict__ pitch, const float* __restrict__ wts,
    float* __restrict__ bs1, float* __restrict__ bs2,
    float* __restrict__ wts_eff, int T)
{
    int t = threadIdx.x;
    if (blockIdx.x >= NB2) {                      // wts_eff part
        int i = (blockIdx.x - NB2) * 256 + t;
        if (i < NWT * WTLEN) {
            float v = wts[i];
            if ((i >> 9) >= 4) v = tanhf(v);
            wts_eff[i] = v;
        }
        return;
    }
    __shared__ float b0[256];
    __shared__ float b1[16];
    int blk = blockIdx.x;
    size_t s0 = (size_t)blk * 4096;
    int nsamp = min(4096, T - (int)s0);
    int nb0 = nsamp >> 4;                         // 256 or 96
    if (t < nb0) {                                // bs0: seq 16-chain of incs
        const float4* p4 = (const float4*)(pitch + s0 + (size_t)t * 16);
        float acc = 0.f;
        #pragma unroll
        for (int i = 0; i < 4; ++i) {
            float4 v = p4[i];
            acc = acc + inc32_of(v.x);
            acc = acc + inc32_of(v.y);
            acc = acc + inc32_of(v.z);
            acc = acc + inc32_of(v.w);
        }
        b0[t] = acc;
    }
    __syncthreads();
    int nb1 = nb0 >> 4;                           // 16 or 6
    if (t < nb1) {                                // bs1: seq 16-chain of bs0
        float acc = b0[t * 16];
        for (int j = 1; j < 16; ++j) acc = acc + b0[t * 16 + j];
        b1[t] = acc;
        bs1[blk * 16 + t] = acc;
    }
    __syncthreads();
    if (t == 0) {                                 // bs2: seq chain (pad -> skip, exact)
        float acc = b1[0];
        for (int j = 1; j < nb1; ++j) acc = acc + b1[j];
        bs2[blk] = acc;
    }
}

// K2: R20's 3-barrier k_main; mixrow w-loop unrolled for load-latency overlap.
__global__ __launch_bounds__(256) void k_main(
    const float* __restrict__ pitch, const float* __restrict__ amp,
    const float* __restrict__ att, const float* __restrict__ wts_eff,
    const float* __restrict__ bs1g, const float* __restrict__ bs2g,
    float* __restrict__ out, int frames)
{
    __shared__ float smT[NWT][SMP];         // 3 KB
    __shared__ float mixrow[FPB][WTLEN];    // 16 KB
    __shared__ float pr[SPB + SPB / 16];    // 5.3 KB, padded indexing
    __shared__ float roffL[SPB / 16];       // 80
    __shared__ float bs2L[NB2P];            // zero-padded
    __shared__ float bs1w[32];              // bs1 rows rlo, rlo+1
    __shared__ float bs3L[NB3];
    __shared__ float S4L[NB3];
    __shared__ float S3w[2];
    __shared__ float S2w[6];
    __shared__ float bs1prevL;

    int tid = threadIdx.x, lane = tid & 63, wv = tid >> 6;   // wv in [0,4)
    int b = blockIdx.x;
    int f0 = b * FPB;
    size_t base = (size_t)b * SPB;
    int j0 = 5 * b - 2;                     // S2 window start
    int rlo = max(j0, 0) >> 4;              // bs1-row window base for S2

    // ======== phase 1: softmax + staging + window loads ========
    #pragma unroll
    for (int r = 0; r < 2; ++r) {
        int f = f0 + wv * 2 + r;
        float a = att[(size_t)lane * frames + f];
        float m = a;
        #pragma unroll
        for (int off = 32; off; off >>= 1) m = fmaxf(m, __shfl_xor(m, off, 64));
        float e = expf(a - m);
        float s = e;
        #pragma unroll
        for (int off = 32; off; off >>= 1) s += __shfl_xor(s, off, 64);
        smT[lane][wv * 2 + r] = e / s;
    }

    float increg[SPB / NTHR];
    #pragma unroll
    for (int i = 0; i < SPB / NTHR; ++i) {
        increg[i] = inc32_of(pitch[base + i * NTHR + tid]);
        pr[PRI(i * NTHR + tid)] = increg[i];
    }
    if (tid < NB2P) {
        bs2L[tid] = (tid < NB2) ? bs2g[tid] : 0.f;
    } else {                                // 16 spare threads: 2 bs1w loads each
        int i = tid - NB2P;                 // 0..15
        #pragma unroll
        for (int k = 0; k < 2; ++k) {
            int idx = i * 2 + k;            // 0..31
            int g = rlo * 16 + idx;
            bs1w[idx] = (g < NB1) ? bs1g[g] : 0.f;
        }
    }
    if (tid == 224) bs1prevL = (b > 0) ? bs1g[5 * b - 1] : 0.f;
    __syncthreads();                        // barrier A

    // ======== phase 2: scan lanes + in-wave ladder, then all lanes mixrow ====
    if (tid < SPB / 16) {
        int a0 = tid * 17;                  // PRI(tid*16 + j) = tid*17 + j
        float acc = pr[a0];
        for (int j = 1; j < 16; ++j) { acc = acc + pr[a0 + j]; pr[a0 + j] = acc; }
    } else if (tid >= 80 && tid < 80 + NB3) {
        int r = tid - 80;                   // bs3 on wave-1 lanes 16..30
        float a = bs2L[r * 16];
        for (int j = 1; j < 16; ++j) a = a + bs2L[r * 16 + j];
        bs3L[r] = a;
    }
    if (tid == 80) {                        // S4 (in-wave after bs3)
        float a = 0.f;
        for (int i = 0; i < NB3; ++i) { a = a + bs3L[i]; S4L[i] = a; }
    }
    if (tid >= 80 && tid < 82) {            // the two S3 values
        int r = rlo - 1 + (tid - 80);
        float v = 0.f;
        if (r >= 0 && r < NB2) {
            int g = r >> 4, p = r & 15;
            float a = bs2L[g * 16];
            for (int k = 1; k <= p; ++k) a = a + bs2L[g * 16 + k];
            v = g ? (a + S4L[g - 1]) : a;
        }
        S3w[tid - 80] = v;
    }
    if (tid >= 80 && tid < 86) {            // the 6 S2 values
        int j = j0 + (tid - 80);
        float v = 0.f;
        if (j >= 0) {
            int r = j >> 4, p = j & 15;
            int o = (r - rlo) * 16;
            float a = bs1w[o];
            for (int q = 1; q <= p; ++q) a = a + bs1w[o + q];
            v = r ? (a + S3w[r - rlo]) : a;
        }
        S2w[tid - 80] = v;
    }
    {
        #pragma unroll
        for (int it = 0; it < 2; ++it) {
            int j = tid + it * NTHR;
            float acc[FPB];
            #pragma unroll
            for (int k = 0; k < FPB; ++k) acc[k] = 0.f;
            #pragma unroll 16
            for (int w = 0; w < NWT; ++w) {
                float v = wts_eff[w * WTLEN + j];
                float4 s0 = *(const float4*)&smT[w][0];
                float4 s1 = *(const float4*)&smT[w][4];
                acc[0] += s0.x * v;  acc[1] += s0.y * v;
                acc[2] += s0.z * v;  acc[3] += s0.w * v;
                acc[4] += s1.x * v;  acc[5] += s1.y * v;
                acc[6] += s1.z * v;  acc[7] += s1.w * v;
            }
            #pragma unroll
            for (int k = 0; k < FPB; ++k) mixrow[k][j] = acc[k];
        }
    }
    __syncthreads();                        // barrier B

    // ======== phase 3: roffL (80 threads) ========
    if (tid < SPB / 16) {
        float v;
        if (tid == 0) {
            v = (b == 0) ? 0.f : (bs1prevL + S2w[0]);
        } else {
            int lr = (tid - 1) >> 4;
            int p  = (tid - 1) & 15;
            float acc = pr[(lr * 16) * 17 + 15];      // PRI(row*16+15) = row*17+15
            for (int q = 1; q <= p; ++q) acc = acc + pr[(lr * 16 + q) * 17 + 15];
            int gr = 5 * b + lr;
            v = gr ? (acc + S2w[lr + 1]) : acc;
        }
        roffL[tid] = v;
    }
    __syncthreads();                        // barrier C

    // ======== phase 4: per-sample finish ========
    #pragma unroll
    for (int i = 0; i < SPB / NTHR; ++i) {
        int tl = i * NTHR + tid;
        size_t tg = base + tl;
        float C = pr[PRI(tl)] + roffL[tl >> 4];
        float sub = C - increg[i];
        float idx = fmodf(sub, 512.0f);
        if (idx < 0.f) idx += 512.f;
        int li = (int)idx;
        float alpha = idx - (float)li;
        int hi = ((int)ceilf(idx)) & (WTLEN - 1);
        int fr = tl / BLKSZ;
        float wlo = mixrow[fr][li];
        float whi = mixrow[fr][hi];
        out[tg] = (wlo + alpha * (whi - wlo)) * amp[tg];
    }
}

extern "C" void kernel_launch(void* const* d_in, const int* in_sizes, int n_in,
                              void* d_out, int out_size, void* d_ws, size_t ws_size,
                              hipStream_t stream) {
    const float* pitch = (const float*)d_in[0];
    const float* amp   = (const float*)d_in[1];
    const float* wts   = (const float*)d_in[2];
    const float* att   = (const float*)d_in[3];

    int T      = in_sizes[0];        // 960000
    int frames = T / BLKSZ;          // 6000
    int nmain  = T / SPB;            // 750

    float* ws      = (float*)d_ws;
    float* wts_eff = ws;                     // 32768 floats
    float* bs1     = ws + 32768;             // 3750 (pad 3840)
    float* bs2     = ws + 32768 + 3840;      // 235  (pad 256)
    float* out     = (float*)d_out;

    int nwts_blocks = (NWT * WTLEN + 255) / 256;       // 128
    k_leaf<<<NB2 + nwts_blocks, 256, 0, stream>>>(pitch, wts, bs1, bs2, wts_eff, T);
    k_main<<<nmain, 256, 0, stream>>>(pitch, amp, att, wts_eff, bs1, bs2, out, frames);
}